// Round 12
// baseline (3127.672 us; speedup 1.0000x reference)
//
#include <hip/hip_runtime.h>

using half8   = __attribute__((ext_vector_type(8))) _Float16;
using f32x16  = __attribute__((ext_vector_type(16))) float;
using float4v = __attribute__((ext_vector_type(4))) float;

#define T_STEPS 256
#define BATCH   512
#define HID     2048
#define KS      128        // HID/16 k-steps
#define HGEN    8          // h generation-pool depth
#define HSLOT   (BATCH * HID / 8)   // half8 elems per h slot (2 MB)
// Fragment order: ((blk32*KS + ks)*64 + lane) * 16B
// lane l: row/col = blk32*32 + (l&31), k = ks*16 + (l>>5)*8 + e

__device__ __forceinline__ f32x16 zero16() {
  f32x16 z;
#pragma unroll
  for (int r = 0; r < 16; ++r) z[r] = 0.0f;
  return z;
}

// LLC-coherent ops (sc0 sc1 = bypass L1/L2, access the device-coherent MALL).
__device__ __forceinline__ float loadf_llc(const float* p) {
  float r;
  asm volatile("global_load_dword %0, %1, off sc0 sc1" : "=v"(r) : "v"(p));
  return r;
}
__device__ __forceinline__ void store16_llc(half8* p, half8 v) {
  asm volatile("global_store_dwordx4 %0, %1, off sc0 sc1" :: "v"(p), "v"(v) : "memory");
}
__device__ __forceinline__ void storef_llc(float* p, float v) {
  asm volatile("global_store_dword %0, %1, off sc0 sc1" :: "v"(p), "v"(v) : "memory");
}

// ---- packing kernels (proven) ----
__global__ void pack_whh_k(const float* __restrict__ whh, half8* __restrict__ bp) {
  int id   = blockIdx.x * 256 + threadIdx.x;
  int lane = id & 63;
  int ks   = (id >> 6) & 127;
  int nblk = id >> 13;
  int j = nblk * 32 + (lane & 31);
  int k = ks * 16 + (lane >> 5) * 8;
  const float4v* src = (const float4v*)(whh + (size_t)j * HID + k);
  float4v a = src[0], b = src[1];
  half8 v;
  v[0]=(_Float16)a[0]; v[1]=(_Float16)a[1]; v[2]=(_Float16)a[2]; v[3]=(_Float16)a[3];
  v[4]=(_Float16)b[0]; v[5]=(_Float16)b[1]; v[6]=(_Float16)b[2]; v[7]=(_Float16)b[3];
  bp[id] = v;
}

__global__ void pack_h_k(const float* __restrict__ hsrc, half8* __restrict__ hp) {
  int id   = blockIdx.x * 256 + threadIdx.x;
  int lane = id & 63;
  int ks   = (id >> 6) & 127;
  int bblk = id >> 13;
  int b = bblk * 32 + (lane & 31);
  int k = ks * 16 + (lane >> 5) * 8;
  const float4v* src = (const float4v*)(hsrc + (size_t)b * HID + k);
  float4v a = src[0], c = src[1];
  half8 v;
  v[0]=(_Float16)a[0]; v[1]=(_Float16)a[1]; v[2]=(_Float16)a[2]; v[3]=(_Float16)a[3];
  v[4]=(_Float16)c[0]; v[5]=(_Float16)c[1]; v[6]=(_Float16)c[2]; v[7]=(_Float16)c[3];
  hp[id] = v;
}

__global__ void bias_k(const float* __restrict__ bih, const float* __restrict__ bhh,
                       float* __restrict__ bias) {
  int i = blockIdx.x * 256 + threadIdx.x;
  if (i < HID) bias[i] = bih[i] + bhh[i];
}

// Canonicalize tf_mask + zero barrier state (reset every launch).
__global__ void tf_expand_k(const int* __restrict__ tf, int* __restrict__ tfc,
                            unsigned* __restrict__ bar) {
  __shared__ int fmt;
  if (threadIdx.x == 0) {
    const unsigned* u = (const unsigned*)tf;
    int all01 = 1;
    for (int i = 0; i < 32; ++i) if (u[i] > 1u) all01 = 0;
    if (all01) {
      int odd0 = 1;
      for (int i = 1; i < 32; i += 2) if (u[i] != 0u) odd0 = 0;
      fmt = odd0 ? 2 : 1;
    } else fmt = 0;
  }
  __syncthreads();
  int i = threadIdx.x;
  int v;
  if (fmt == 2)      v = tf[2 * i];
  else if (fmt == 1) v = tf[i];
  else               v = (int)((const unsigned char*)tf)[i];
  tfc[i] = v ? 1 : 0;
  bar[i] = 0u;
}

// ---- persistent RNN kernel ----
// 256 blocks x 512 thr (8 waves), ~90KB LDS -> 1 block/CU, co-resident.
// STATIC m = bid&7, n = bid>>3 (placement-independent, r10-proven).
// h transport: 8-slot generation pool. Step t WRITES slot t%8 via sc0+sc1
// (-> device-coherent MALL); step t+1 READS with NORMAL cached loads.
// Safety: a stale cached line would have to survive 8 steps in a 4MB L2
// with ~2MB/step inflow (and L1 turns over 8x/step) -> capacity-impossible.
// Cross-replay staleness: one acquire-agent fence at kernel entry (invalidates
// L1+L2 once; r4 evidence). ypg/out stay on the LLC path (sc0 sc1).
// Sync: per-m 32-arrival monotonic LLC atomic barrier, every step (r10).
// Epilogue: scalar LDS, conflict-free. Do NOT vectorize to b128 (r7/r8:
// register cliff -> scratch spill). bar layout: bar[m*32] arrive counter.
__global__ __launch_bounds__(512) void rnn_persist(
    const float* __restrict__ x0,   const float* __restrict__ tgt,
    const int*   __restrict__ tfc,  const float* __restrict__ wih,
    const float* __restrict__ wout, const float* __restrict__ bias,
    const float* __restrict__ bout, const half8* __restrict__ wp,
    half8* __restrict__ hpool,      float* __restrict__ ypg,
    float* __restrict__ out,        unsigned* __restrict__ bar) {
  __shared__ float part[4][64][68];
  __shared__ float hs[64][68];
  __shared__ float xs[64];
  __shared__ float ypart[8][64];
  __shared__ float wih_s[64], wout_s[64], bias_s[64];
  __shared__ int   tfs[T_STEPS];

  // Kill any stale L1/L2 lines from a previous graph replay (once per launch).
  __builtin_amdgcn_fence(__ATOMIC_ACQUIRE, "agent");

  const int bid = blockIdx.x;
  const int m = bid & 7;      // batch rows m*64..+64
  const int n = bid >> 3;     // hidden cols n*64..+64
  const int tid = threadIdx.x;
  const int w = tid >> 6;     // wave = k-eighth
  const int l = tid & 63;
  const int hi = l >> 5;
  const int c = l & 31;

  const float bo = bout[0];

  if (tid < 64) {
    int j = n * 64 + tid;
    wih_s[tid]  = wih[j];
    wout_s[tid] = wout[j];
    bias_s[tid] = bias[j];
  }
  if (tid < T_STEPS) tfs[tid] = tfc[tid];

  // persistent W fragments: 32 half8 = 128 VGPR (read-only, cached loads)
  half8 wb0[16], wb1[16];
  {
    const half8* b0p = wp + ((size_t)(2 * n + 0) * KS + w * 16) * 64 + l;
    const half8* b1p = wp + ((size_t)(2 * n + 1) * KS + w * 16) * 64 + l;
#pragma unroll
    for (int i = 0; i < 16; ++i) { wb0[i] = b0p[i * 64]; wb1[i] = b1p[i * 64]; }
  }
  __syncthreads();

  for (int t = 0; t < T_STEPS; ++t) {
    const half8* hr = hpool + (size_t)((t + HGEN - 1) % HGEN) * HSLOT;  // h_{t-1}
    half8*       hw = hpool + (size_t)(t % HGEN) * HSLOT;               // h_t

    // x feedback at step top: wave 0's LLC latency overlaps waves 1-7's A-stream.
    // ypg of step t-1 is barrier-protected. xs only read in phase 3.
    if (tid < 64) {
      float x;
      if (t == 0) {
        x = x0[m * 64 + tid];
      } else {
        const float* yp = ypg + ((size_t)((t - 1) & 1) * 8 + m) * 2048 + tid;
        float a[32];
#pragma unroll
        for (int i = 0; i < 32; ++i) a[i] = loadf_llc(yp + i * 64);
        asm volatile("s_waitcnt vmcnt(0)" ::: "memory");
        __builtin_amdgcn_sched_barrier(0);
        float s = 0.0f;
#pragma unroll
        for (int i = 0; i < 32; ++i) s += a[i];   // fixed order: deterministic
        float ysum = s + bo;
        if (n == 0) out[(size_t)(t - 1) * BATCH + m * 64 + tid] = ysum;
        x = tfs[t - 1] ? tgt[(size_t)(t - 1) * BATCH + m * 64 + tid] : ysum;
      }
      xs[tid] = x;
    }

    // A-stream: NORMAL cached loads (L1/L2!), 4 batches; compiler pipelines.
    f32x16 acc00 = zero16(), acc01 = zero16(), acc10 = zero16(), acc11 = zero16();
    {
      const half8* a0p = hr + ((size_t)(2 * m + 0) * KS + w * 16) * 64 + l;
      const half8* a1p = hr + ((size_t)(2 * m + 1) * KS + w * 16) * 64 + l;
#pragma unroll
      for (int kk = 0; kk < 4; ++kk) {
        half8 a0[4], a1[4];
#pragma unroll
        for (int i = 0; i < 4; ++i) {
          a0[i] = a0p[(kk * 4 + i) * 64];
          a1[i] = a1p[(kk * 4 + i) * 64];
        }
#pragma unroll
        for (int i = 0; i < 4; ++i) {
          acc00 = __builtin_amdgcn_mfma_f32_32x32x16_f16(a0[i], wb0[kk * 4 + i], acc00, 0, 0, 0);
          acc01 = __builtin_amdgcn_mfma_f32_32x32x16_f16(a0[i], wb1[kk * 4 + i], acc01, 0, 0, 0);
          acc10 = __builtin_amdgcn_mfma_f32_32x32x16_f16(a1[i], wb0[kk * 4 + i], acc10, 0, 0, 0);
          acc11 = __builtin_amdgcn_mfma_f32_32x32x16_f16(a1[i], wb1[kk * 4 + i], acc11, 0, 0, 0);
        }
      }
    }

    // C/D layout: col = lane&31, row = (reg&3) + 8*(reg>>2) + 4*(lane>>5)
    // phase 1: waves 0-3 store partials (scalar, conflict-free)
    if (w < 4) {
#pragma unroll
      for (int r = 0; r < 16; ++r) {
        int row0 = (r & 3) + 8 * (r >> 2) + 4 * hi;
        part[w][row0     ][c     ] = acc00[r];
        part[w][row0     ][c + 32] = acc01[r];
        part[w][row0 + 32][c     ] = acc10[r];
        part[w][row0 + 32][c + 32] = acc11[r];
      }
    }
    __syncthreads();
    // phase 2: waves 4-7 accumulate in place (same lane pattern -> no races)
    if (w >= 4) {
      int ww = w - 4;
#pragma unroll
      for (int r = 0; r < 16; ++r) {
        int row0 = (r & 3) + 8 * (r >> 2) + 4 * hi;
        part[ww][row0     ][c     ] += acc00[r];
        part[ww][row0     ][c + 32] += acc01[r];
        part[ww][row0 + 32][c     ] += acc10[r];
        part[ww][row0 + 32][c + 32] += acc11[r];
      }
    }
    __syncthreads();

    // phase 3: octant combine + bias + rank-1 input, fast tanh (r2-proven)
    {
      int mb = w & 1, nb = (w >> 1) & 1, rh = w >> 2;
#pragma unroll
      for (int r = 0; r < 8; ++r) {
        int rr = rh * 8 + r;
        int row = mb * 32 + (rr & 3) + 8 * (rr >> 2) + 4 * hi;
        int col = nb * 32 + c;
        float s = part[0][row][col] + part[1][row][col]
                + part[2][row][col] + part[3][row][col];
        s += bias_s[col] + xs[row] * wih_s[col];
        float e = __expf(2.0f * s);
        hs[row][col] = 1.0f - 2.0f / (e + 1.0f);   // tanh(s)
      }
    }
    __syncthreads();

    // repack h_t to A-fragment layout (LLC stores) + y partials
    {
      int row = tid & 63;
      int g   = tid >> 6;
      float hv[8];
      float4v v0 = *(const float4v*)&hs[row][g * 8];
      float4v v1 = *(const float4v*)&hs[row][g * 8 + 4];
      hv[0]=v0[0]; hv[1]=v0[1]; hv[2]=v0[2]; hv[3]=v0[3];
      hv[4]=v1[0]; hv[5]=v1[1]; hv[6]=v1[2]; hv[7]=v1[3];

      float yp = 0.0f;
#pragma unroll
      for (int e = 0; e < 8; ++e) yp += hv[e] * wout_s[g * 8 + e];
      ypart[g][row] = yp;

      half8 f;
#pragma unroll
      for (int e = 0; e < 8; ++e) f[e] = (_Float16)hv[e];
      int bblk = 2 * m + (row >> 5);
      int ksg  = n * 4 + (g >> 1);
      int lane = (g & 1) * 32 + (row & 31);
      store16_llc(hw + ((size_t)bblk * KS + ksg) * 64 + lane, f);
    }
    __syncthreads();   // all waves' h stores acked at MALL (vmcnt 0 at barrier)

    // wave 0: block's y partial -> ypg[t&1][m][n] (LLC)
    if (w == 0) {
      float y = ypart[0][l] + ypart[1][l] + ypart[2][l] + ypart[3][l]
              + ypart[4][l] + ypart[5][l] + ypart[6][l] + ypart[7][l];
      storef_llc(ypg + (((size_t)(t & 1) * 8 + m) * 32 + n) * 64 + l, y);
      asm volatile("s_waitcnt vmcnt(0)" ::: "memory");   // ypg at MALL pre-arrival
    }

    // per-m barrier: 32 arrivals, monotonic LLC atomic counter, every step.
    if (tid == 0) {
      __hip_atomic_fetch_add(&bar[m * 32], 1u, __ATOMIC_RELAXED,
                             __HIP_MEMORY_SCOPE_AGENT);
      unsigned tgt_cnt = 32u * (unsigned)(t + 1);
      while (__hip_atomic_load(&bar[m * 32], __ATOMIC_RELAXED,
                               __HIP_MEMORY_SCOPE_AGENT) < tgt_cnt)
        __builtin_amdgcn_s_sleep(1);
    }
    __syncthreads();
  }

  // final output row (t = T-1): barrier above makes all ypg slices visible
  if (n == 0 && tid < 64) {
    const float* yp = ypg + ((size_t)((T_STEPS - 1) & 1) * 8 + m) * 2048 + tid;
    float a[32];
#pragma unroll
    for (int i = 0; i < 32; ++i) a[i] = loadf_llc(yp + i * 64);
    asm volatile("s_waitcnt vmcnt(0)" ::: "memory");
    __builtin_amdgcn_sched_barrier(0);
    float s = 0.0f;
#pragma unroll
    for (int i = 0; i < 32; ++i) s += a[i];
    out[(size_t)(T_STEPS - 1) * BATCH + m * 64 + tid] = s + bo;
  }
}

extern "C" void kernel_launch(void* const* d_in, const int* in_sizes, int n_in,
                              void* d_out, int out_size, void* d_ws, size_t ws_size,
                              hipStream_t stream) {
  (void)in_sizes; (void)n_in; (void)out_size; (void)ws_size;
  const float* x0   = (const float*)d_in[0];
  const float* hid  = (const float*)d_in[1];
  const float* tgt  = (const float*)d_in[2];
  const float* wih  = (const float*)d_in[3];
  const float* bih  = (const float*)d_in[4];
  const float* whh  = (const float*)d_in[5];
  const float* bhh  = (const float*)d_in[6];
  const float* wout = (const float*)d_in[7];
  const float* bout = (const float*)d_in[8];
  const int*   tf   = (const int*)d_in[9];
  float* out = (float*)d_out;

  char* ws = (char*)d_ws;
  half8*    wp    = (half8*)ws;                            // 8 MB packed W_hh fp16
  half8*    hpool = (half8*)(ws + (8u << 20));             // 16 MB: 8 x 2MB h slots
  float*    bias  = (float*)(ws + (24u << 20));            // 8 KB
  int*      tfc   = (int*)  (ws + (24u << 20) + 8192);     // 1 KB
  unsigned* bar   = (unsigned*)(ws + (24u << 20) + 16384); // 1 KB barrier
  float*    ypg   = (float*)(ws + (24u << 20) + 32768);    // 128 KB y partials

  pack_whh_k <<<2048, 256, 0, stream>>>(whh, wp);
  // initial h -> pool slot HGEN-1 (read by step t=0)
  pack_h_k   <<<512,  256, 0, stream>>>(hid, hpool + (size_t)(HGEN - 1) * HSLOT);
  bias_k     <<<8,    256, 0, stream>>>(bih, bhh, bias);
  tf_expand_k<<<1,    256, 0, stream>>>(tf, tfc, bar);

  rnn_persist<<<256, 512, 0, stream>>>(x0, tgt, tfc, wih, wout, bias, bout,
                                       wp, hpool, ypg, out, bar);
}

// Round 13
// 2033.746 us; speedup vs baseline: 1.5379x; 1.5379x over previous
//
#include <hip/hip_runtime.h>

using half8   = __attribute__((ext_vector_type(8))) _Float16;
using f32x16  = __attribute__((ext_vector_type(16))) float;
using float4v = __attribute__((ext_vector_type(4))) float;

#define T_STEPS 256
#define BATCH   512
#define HID     2048
#define KS      128   // HID/16 k-steps
// Fragment order: ((blk32*KS + ks)*64 + lane) * 16B
// lane l: row/col = blk32*32 + (l&31), k = ks*16 + (l>>5)*8 + e

__device__ __forceinline__ f32x16 zero16() {
  f32x16 z;
#pragma unroll
  for (int r = 0; r < 16; ++r) z[r] = 0.0f;
  return z;
}

// LLC-coherent ops (sc0 sc1 = bypass L1/L2, device-coherent MALL). r10-proven.
__device__ __forceinline__ half8 load16_llc(const half8* p) {
  half8 r;
  asm volatile("global_load_dwordx4 %0, %1, off sc0 sc1" : "=v"(r) : "v"(p));
  return r;
}
__device__ __forceinline__ float loadf_llc(const float* p) {
  float r;
  asm volatile("global_load_dword %0, %1, off sc0 sc1" : "=v"(r) : "v"(p));
  return r;
}
__device__ __forceinline__ void store16_llc(half8* p, half8 v) {
  asm volatile("global_store_dwordx4 %0, %1, off sc0 sc1" :: "v"(p), "v"(v) : "memory");
}
__device__ __forceinline__ void storef_llc(float* p, float v) {
  asm volatile("global_store_dword %0, %1, off sc0 sc1" :: "v"(p), "v"(v) : "memory");
}

// ---- packing kernels (proven) ----
__global__ void pack_whh_k(const float* __restrict__ whh, half8* __restrict__ bp) {
  int id   = blockIdx.x * 256 + threadIdx.x;
  int lane = id & 63;
  int ks   = (id >> 6) & 127;
  int nblk = id >> 13;
  int j = nblk * 32 + (lane & 31);
  int k = ks * 16 + (lane >> 5) * 8;
  const float4v* src = (const float4v*)(whh + (size_t)j * HID + k);
  float4v a = src[0], b = src[1];
  half8 v;
  v[0]=(_Float16)a[0]; v[1]=(_Float16)a[1]; v[2]=(_Float16)a[2]; v[3]=(_Float16)a[3];
  v[4]=(_Float16)b[0]; v[5]=(_Float16)b[1]; v[6]=(_Float16)b[2]; v[7]=(_Float16)b[3];
  bp[id] = v;
}

__global__ void pack_h_k(const float* __restrict__ hsrc, half8* __restrict__ hp) {
  int id   = blockIdx.x * 256 + threadIdx.x;
  int lane = id & 63;
  int ks   = (id >> 6) & 127;
  int bblk = id >> 13;
  int b = bblk * 32 + (lane & 31);
  int k = ks * 16 + (lane >> 5) * 8;
  const float4v* src = (const float4v*)(hsrc + (size_t)b * HID + k);
  float4v a = src[0], c = src[1];
  half8 v;
  v[0]=(_Float16)a[0]; v[1]=(_Float16)a[1]; v[2]=(_Float16)a[2]; v[3]=(_Float16)a[3];
  v[4]=(_Float16)c[0]; v[5]=(_Float16)c[1]; v[6]=(_Float16)c[2]; v[7]=(_Float16)c[3];
  hp[id] = v;
}

__global__ void bias_k(const float* __restrict__ bih, const float* __restrict__ bhh,
                       float* __restrict__ bias) {
  int i = blockIdx.x * 256 + threadIdx.x;
  if (i < HID) bias[i] = bih[i] + bhh[i];
}

// Canonicalize tf_mask + zero barrier state (reset every launch).
__global__ void tf_expand_k(const int* __restrict__ tf, int* __restrict__ tfc,
                            unsigned* __restrict__ bar) {
  __shared__ int fmt;
  if (threadIdx.x == 0) {
    const unsigned* u = (const unsigned*)tf;
    int all01 = 1;
    for (int i = 0; i < 32; ++i) if (u[i] > 1u) all01 = 0;
    if (all01) {
      int odd0 = 1;
      for (int i = 1; i < 32; i += 2) if (u[i] != 0u) odd0 = 0;
      fmt = odd0 ? 2 : 1;
    } else fmt = 0;
  }
  __syncthreads();
  int i = threadIdx.x;
  int v;
  if (fmt == 2)      v = tf[2 * i];
  else if (fmt == 1) v = tf[i];
  else               v = (int)((const unsigned char*)tf)[i];
  tfc[i] = v ? 1 : 0;
  bar[i] = 0u;
}

// ---- persistent RNN kernel ----
// r10 structure (2036us, twice-validated): 256 blocks x 512 thr, ~90KB LDS ->
// 1 block/CU. STATIC m = bid&7, n = bid>>3. All cross-block dataflow (h, ypg)
// via sc0+sc1 -> device-coherent MALL, placement-independent. Per-m 32-arrival
// monotonic LLC atomic barrier every step. Scalar LDS epilogue (b128 spills:
// r7/r8). This round: (1) counted-vmcnt A-pipeline (8 half-batches of 4 loads,
// lookahead 1, vmcnt(4); register-neutral ha[2][4]); (2) feedback distributed
// across all 8 waves (4 ypg loads each, issued ahead of A-loads, drained by
// the same counted waits), wave 0 finalizes xs from LDS partials in the
// sync1->sync2 window. bar layout: bar[m*32] arrive counter.
__global__ __launch_bounds__(512) void rnn_persist(
    const float* __restrict__ x0,   const float* __restrict__ tgt,
    const int*   __restrict__ tfc,  const float* __restrict__ wih,
    const float* __restrict__ wout, const float* __restrict__ bias,
    const float* __restrict__ bout, const half8* __restrict__ wp,
    half8* __restrict__ h0,         half8* __restrict__ h1,
    float* __restrict__ ypg,        float* __restrict__ out,
    unsigned* __restrict__ bar) {
  __shared__ float part[4][64][68];
  __shared__ float hs[64][68];
  __shared__ float xs[64];
  __shared__ float ypart[8][64];
  __shared__ float yfb[8][64];     // distributed feedback partials
  __shared__ float wih_s[64], wout_s[64], bias_s[64];
  __shared__ int   tfs[T_STEPS];

  const int bid = blockIdx.x;
  const int m = bid & 7;      // batch rows m*64..+64
  const int n = bid >> 3;     // hidden cols n*64..+64
  const int tid = threadIdx.x;
  const int w = tid >> 6;     // wave = k-eighth
  const int l = tid & 63;
  const int hi = l >> 5;
  const int c = l & 31;

  const float bo = bout[0];

  if (tid < 64) {
    int j = n * 64 + tid;
    wih_s[tid]  = wih[j];
    wout_s[tid] = wout[j];
    bias_s[tid] = bias[j];
  }
  if (tid < T_STEPS) tfs[tid] = tfc[tid];

  // persistent W fragments: 32 half8 = 128 regs (read-only, cached loads)
  half8 wb0[16], wb1[16];
  {
    const half8* b0p = wp + ((size_t)(2 * n + 0) * KS + w * 16) * 64 + l;
    const half8* b1p = wp + ((size_t)(2 * n + 1) * KS + w * 16) * 64 + l;
#pragma unroll
    for (int i = 0; i < 16; ++i) { wb0[i] = b0p[i * 64]; wb1[i] = b1p[i * 64]; }
  }
  __syncthreads();

  for (int t = 0; t < T_STEPS; ++t) {
    const half8* hr = (t & 1) ? h1 : h0;
    half8*       hw = (t & 1) ? h0 : h1;

    // distributed feedback: this thread loads 4 of the 32 ypg partials for
    // row l (partial indices w*4..w*4+3). Issued BEFORE the A-loads; drained
    // by the pipeline's counted waits (FIFO: these complete first).
    float fb0 = 0.f, fb1 = 0.f, fb2 = 0.f, fb3 = 0.f;
    if (t > 0) {
      const float* yp = ypg + ((size_t)((t - 1) & 1) * 8 + m) * 2048 + l;
      fb0 = loadf_llc(yp + (w * 4 + 0) * 64);
      fb1 = loadf_llc(yp + (w * 4 + 1) * 64);
      fb2 = loadf_llc(yp + (w * 4 + 2) * 64);
      fb3 = loadf_llc(yp + (w * 4 + 3) * 64);
    }

    // A-pipeline: 8 half-batches of 4 loads, lookahead 1, counted vmcnt.
    f32x16 acc00 = zero16(), acc01 = zero16(), acc10 = zero16(), acc11 = zero16();
    {
      const half8* a0p = hr + ((size_t)(2 * m + 0) * KS + w * 16) * 64 + l;
      const half8* a1p = hr + ((size_t)(2 * m + 1) * KS + w * 16) * 64 + l;
      half8 ha[2][4];
      // prologue: half-batch 0 (ks pair 0,1)
      ha[0][0] = load16_llc(a0p + 0 * 64);
      ha[0][1] = load16_llc(a0p + 1 * 64);
      ha[0][2] = load16_llc(a1p + 0 * 64);
      ha[0][3] = load16_llc(a1p + 1 * 64);
#pragma unroll
      for (int i = 0; i < 8; ++i) {
        const int cur = i & 1, nxt = cur ^ 1;
        if (i < 7) {
          ha[nxt][0] = load16_llc(a0p + (2 * i + 2) * 64);
          ha[nxt][1] = load16_llc(a0p + (2 * i + 3) * 64);
          ha[nxt][2] = load16_llc(a1p + (2 * i + 2) * 64);
          ha[nxt][3] = load16_llc(a1p + (2 * i + 3) * 64);
          asm volatile("s_waitcnt vmcnt(4)" ::: "memory");
        } else {
          asm volatile("s_waitcnt vmcnt(0)" ::: "memory");
        }
        __builtin_amdgcn_sched_barrier(0);
        acc00 = __builtin_amdgcn_mfma_f32_32x32x16_f16(ha[cur][0], wb0[2 * i], acc00, 0, 0, 0);
        acc01 = __builtin_amdgcn_mfma_f32_32x32x16_f16(ha[cur][0], wb1[2 * i], acc01, 0, 0, 0);
        acc10 = __builtin_amdgcn_mfma_f32_32x32x16_f16(ha[cur][2], wb0[2 * i], acc10, 0, 0, 0);
        acc11 = __builtin_amdgcn_mfma_f32_32x32x16_f16(ha[cur][2], wb1[2 * i], acc11, 0, 0, 0);
        acc00 = __builtin_amdgcn_mfma_f32_32x32x16_f16(ha[cur][1], wb0[2 * i + 1], acc00, 0, 0, 0);
        acc01 = __builtin_amdgcn_mfma_f32_32x32x16_f16(ha[cur][1], wb1[2 * i + 1], acc01, 0, 0, 0);
        acc10 = __builtin_amdgcn_mfma_f32_32x32x16_f16(ha[cur][3], wb0[2 * i + 1], acc10, 0, 0, 0);
        acc11 = __builtin_amdgcn_mfma_f32_32x32x16_f16(ha[cur][3], wb1[2 * i + 1], acc11, 0, 0, 0);
      }
    }

    // feedback partial (loads drained by the vmcnt(0) above; fixed order)
    if (t > 0) yfb[w][l] = (fb0 + fb1) + (fb2 + fb3);

    // C/D layout: col = lane&31, row = (reg&3) + 8*(reg>>2) + 4*(lane>>5)
    // phase 1: waves 0-3 store partials (scalar, conflict-free)
    if (w < 4) {
#pragma unroll
      for (int r = 0; r < 16; ++r) {
        int row0 = (r & 3) + 8 * (r >> 2) + 4 * hi;
        part[w][row0     ][c     ] = acc00[r];
        part[w][row0     ][c + 32] = acc01[r];
        part[w][row0 + 32][c     ] = acc10[r];
        part[w][row0 + 32][c + 32] = acc11[r];
      }
    }
    __syncthreads();

    // phase 2: waves 4-7 accumulate in place; wave 0 finalizes xs in parallel
    if (w >= 4) {
      int ww = w - 4;
#pragma unroll
      for (int r = 0; r < 16; ++r) {
        int row0 = (r & 3) + 8 * (r >> 2) + 4 * hi;
        part[ww][row0     ][c     ] += acc00[r];
        part[ww][row0     ][c + 32] += acc01[r];
        part[ww][row0 + 32][c     ] += acc10[r];
        part[ww][row0 + 32][c + 32] += acc11[r];
      }
    } else if (w == 0) {
      float x;
      if (t == 0) {
        x = x0[m * 64 + l];
      } else {
        float s = ((yfb[0][l] + yfb[1][l]) + (yfb[2][l] + yfb[3][l]))
                + ((yfb[4][l] + yfb[5][l]) + (yfb[6][l] + yfb[7][l]));
        float ysum = s + bo;
        if (n == 0) out[(size_t)(t - 1) * BATCH + m * 64 + l] = ysum;
        x = tfs[t - 1] ? tgt[(size_t)(t - 1) * BATCH + m * 64 + l] : ysum;
      }
      xs[l] = x;
    }
    __syncthreads();

    // phase 3: octant combine + bias + rank-1 input, fast tanh (r9/r10-proven)
    {
      int mb = w & 1, nb = (w >> 1) & 1, rh = w >> 2;
#pragma unroll
      for (int r = 0; r < 8; ++r) {
        int rr = rh * 8 + r;
        int row = mb * 32 + (rr & 3) + 8 * (rr >> 2) + 4 * hi;
        int col = nb * 32 + c;
        float s = part[0][row][col] + part[1][row][col]
                + part[2][row][col] + part[3][row][col];
        s += bias_s[col] + xs[row] * wih_s[col];
        float e = __expf(2.0f * s);
        hs[row][col] = 1.0f - 2.0f / (e + 1.0f);   // tanh(s)
      }
    }
    __syncthreads();

    // repack h_t to A-fragment layout (LLC stores) + y partials
    {
      int row = tid & 63;
      int g   = tid >> 6;
      float hv[8];
      float4v v0 = *(const float4v*)&hs[row][g * 8];
      float4v v1 = *(const float4v*)&hs[row][g * 8 + 4];
      hv[0]=v0[0]; hv[1]=v0[1]; hv[2]=v0[2]; hv[3]=v0[3];
      hv[4]=v1[0]; hv[5]=v1[1]; hv[6]=v1[2]; hv[7]=v1[3];

      float yp = 0.0f;
#pragma unroll
      for (int e = 0; e < 8; ++e) yp += hv[e] * wout_s[g * 8 + e];
      ypart[g][row] = yp;

      half8 f;
#pragma unroll
      for (int e = 0; e < 8; ++e) f[e] = (_Float16)hv[e];
      int bblk = 2 * m + (row >> 5);
      int ksg  = n * 4 + (g >> 1);
      int lane = (g & 1) * 32 + (row & 31);
      store16_llc(hw + ((size_t)bblk * KS + ksg) * 64 + lane, f);
    }
    __syncthreads();   // all waves' h stores acked at MALL (vmcnt 0 at barrier)

    // wave 0: block's y partial -> ypg[t&1][m][n] (LLC)
    if (w == 0) {
      float y = ypart[0][l] + ypart[1][l] + ypart[2][l] + ypart[3][l]
              + ypart[4][l] + ypart[5][l] + ypart[6][l] + ypart[7][l];
      storef_llc(ypg + (((size_t)(t & 1) * 8 + m) * 32 + n) * 64 + l, y);
      asm volatile("s_waitcnt vmcnt(0)" ::: "memory");   // ypg at MALL pre-arrival
    }

    // per-m barrier: 32 arrivals, monotonic LLC atomic counter, every step.
    if (tid == 0) {
      __hip_atomic_fetch_add(&bar[m * 32], 1u, __ATOMIC_RELAXED,
                             __HIP_MEMORY_SCOPE_AGENT);
      unsigned tgt_cnt = 32u * (unsigned)(t + 1);
      while (__hip_atomic_load(&bar[m * 32], __ATOMIC_RELAXED,
                               __HIP_MEMORY_SCOPE_AGENT) < tgt_cnt)
        __builtin_amdgcn_s_sleep(1);
    }
    __syncthreads();
  }

  // final output row (t = T-1): barrier above makes all ypg slices visible
  if (n == 0 && tid < 64) {
    const float* yp = ypg + ((size_t)((T_STEPS - 1) & 1) * 8 + m) * 2048 + tid;
    float a[32];
#pragma unroll
    for (int i = 0; i < 32; ++i) a[i] = loadf_llc(yp + i * 64);
    asm volatile("s_waitcnt vmcnt(0)" ::: "memory");
    __builtin_amdgcn_sched_barrier(0);
    float s = 0.0f;
#pragma unroll
    for (int i = 0; i < 32; ++i) s += a[i];
    out[(size_t)(T_STEPS - 1) * BATCH + m * 64 + tid] = s + bo;
  }
}

extern "C" void kernel_launch(void* const* d_in, const int* in_sizes, int n_in,
                              void* d_out, int out_size, void* d_ws, size_t ws_size,
                              hipStream_t stream) {
  (void)in_sizes; (void)n_in; (void)out_size; (void)ws_size;
  const float* x0   = (const float*)d_in[0];
  const float* hid  = (const float*)d_in[1];
  const float* tgt  = (const float*)d_in[2];
  const float* wih  = (const float*)d_in[3];
  const float* bih  = (const float*)d_in[4];
  const float* whh  = (const float*)d_in[5];
  const float* bhh  = (const float*)d_in[6];
  const float* wout = (const float*)d_in[7];
  const float* bout = (const float*)d_in[8];
  const int*   tf   = (const int*)d_in[9];
  float* out = (float*)d_out;

  char* ws = (char*)d_ws;
  half8*    wp   = (half8*)ws;                            // 8 MB packed W_hh fp16
  half8*    h0   = (half8*)(ws + (8u  << 20));            // 2 MB packed h (ping)
  half8*    h1   = (half8*)(ws + (10u << 20));            // 2 MB packed h (pong)
  float*    bias = (float*)(ws + (12u << 20));            // 8 KB
  int*      tfc  = (int*)  (ws + (12u << 20) + 8192);     // 1 KB
  unsigned* bar  = (unsigned*)(ws + (12u << 20) + 16384); // 1 KB barrier
  float*    ypg  = (float*)(ws + (12u << 20) + 32768);    // 128 KB y partials

  pack_whh_k <<<2048, 256, 0, stream>>>(whh, wp);
  pack_h_k   <<<512,  256, 0, stream>>>(hid, h0);
  bias_k     <<<8,    256, 0, stream>>>(bih, bhh, bias);
  tf_expand_k<<<1,    256, 0, stream>>>(tf, tfc, bar);

  rnn_persist<<<256, 512, 0, stream>>>(x0, tgt, tfc, wih, wout, bias, bout,
                                       wp, h0, h1, ypg, out, bar);
}